// Round 1
// baseline (720.708 us; speedup 1.0000x reference)
//
#include <hip/hip_runtime.h>
#include <hip/hip_bf16.h>
#include <math.h>

// Problem constants
// B=16, H=W=56, C=384, WS=8, SHIFT=4, NH=12, hd=32, N=64, nW=49, B_=784
// rows (tokens) = 16*56*56 = 50176
#define ROWS 50176

typedef short s16;
typedef __attribute__((ext_vector_type(4))) float f32x4;
typedef __attribute__((ext_vector_type(8))) short s16x8;
typedef __attribute__((ext_vector_type(8))) __bf16 bf16x8;

__device__ __forceinline__ s16 f2bf(float f) {
  unsigned u = __float_as_uint(f);
  u = (u + 0x7fffu + ((u >> 16) & 1u)) >> 16;  // RNE
  return (s16)u;
}

// ---- weight convert + transpose: src[K][N] f32 -> dst[N][K] bf16 ----
__global__ void convT(const float* __restrict__ src, s16* __restrict__ dst, int K, int N) {
  int i = blockIdx.x * 256 + threadIdx.x;
  if (i >= K * N) return;
  int n = i / K, k = i - n * K;
  dst[i] = f2bf(src[(size_t)k * N + n]);
}

// ---- LayerNorm f32 -> bf16; window_map=1 applies roll(-4,-4)+window partition on the
//      SOURCE index so output rows are already in window order ----
__global__ __launch_bounds__(256) void ln_k(const float* __restrict__ x,
    const float* __restrict__ g, const float* __restrict__ b,
    s16* __restrict__ out, int window_map) {
  int r = blockIdx.x * 4 + (threadIdx.x >> 6);
  int lane = threadIdx.x & 63;
  size_t src;
  if (window_map) {
    int w = r >> 6, t = r & 63;
    int bb = w / 49, wi = w - bb * 49;
    int wh = wi / 7, ww = wi - wh * 7;
    int i = (wh * 8 + (t >> 3) + 4) % 56;   // roll -SHIFT: src = pos + 4 (mod 56)
    int j = (ww * 8 + (t & 7) + 4) % 56;
    src = (size_t)bb * 3136 + i * 56 + j;
  } else {
    src = (size_t)r;
  }
  const float* xr = x + src * 384;
  float v[6];
  float s = 0.f;
#pragma unroll
  for (int e = 0; e < 6; ++e) { v[e] = xr[lane + e * 64]; s += v[e]; }
#pragma unroll
  for (int o = 1; o < 64; o <<= 1) s += __shfl_xor(s, o, 64);
  float mu = s * (1.f / 384.f);
  float q = 0.f;
#pragma unroll
  for (int e = 0; e < 6; ++e) { float d = v[e] - mu; q += d * d; }
#pragma unroll
  for (int o = 1; o < 64; o <<= 1) q += __shfl_xor(q, o, 64);
  float rs = rsqrtf(q * (1.f / 384.f) + 1e-5f);
  s16* orow = out + (size_t)r * 384;
#pragma unroll
  for (int e = 0; e < 6; ++e) {
    int c = lane + e * 64;
    orow[c] = f2bf((v[e] - mu) * rs * g[c] + b[c]);
  }
}

// ---- GEMM  C[M,N] = A[M,K]bf16 * BT[N,K]bf16 + bias, with fused epilogues ----
// EPI 0: bf16 out (qkv) | 1: window-reverse+unroll + residual(x) -> f32 y (proj)
// EPI 2: exact GELU -> bf16 (fc1) | 3: residual(y) -> f32 y (fc2)
template<int EPI>
__global__ __launch_bounds__(256) void gemm_bt(const s16* __restrict__ A,
    const s16* __restrict__ BT, const float* __restrict__ bias, int K, int N,
    s16* __restrict__ obf, float* of, const float* res) {
  __shared__ s16 Asm[128][40];  // +8 pad: 80B row stride (16B aligned, conflict-light)
  __shared__ s16 Bsm[128][40];
  const int t = threadIdx.x;
  const int m0 = blockIdx.y * 128, n0 = blockIdx.x * 128;
  const int wv = t >> 6, lane = t & 63;
  const int wr = wv >> 1, wc = wv & 1;
  const int lr = lane & 15, lg = lane >> 4;

  f32x4 acc[4][4] = {};

  const s16* gsrc;
  s16* ldst;
  if (t < 128) { gsrc = A + (size_t)(m0 + t) * K;        ldst = &Asm[t][0]; }
  else         { gsrc = BT + (size_t)(n0 + t - 128) * K; ldst = &Bsm[t - 128][0]; }

  for (int k0 = 0; k0 < K; k0 += 32) {
    __syncthreads();
#pragma unroll
    for (int u = 0; u < 4; ++u)
      *reinterpret_cast<s16x8*>(ldst + u * 8) =
          *reinterpret_cast<const s16x8*>(gsrc + k0 + u * 8);
    __syncthreads();
    bf16x8 af[4], bv[4];
#pragma unroll
    for (int m = 0; m < 4; ++m)
      af[m] = *reinterpret_cast<const bf16x8*>(&Asm[wr * 64 + m * 16 + lr][lg * 8]);
#pragma unroll
    for (int n = 0; n < 4; ++n)
      bv[n] = *reinterpret_cast<const bf16x8*>(&Bsm[wc * 64 + n * 16 + lr][lg * 8]);
#pragma unroll
    for (int m = 0; m < 4; ++m)
#pragma unroll
      for (int n = 0; n < 4; ++n)
        acc[m][n] = __builtin_amdgcn_mfma_f32_16x16x32_bf16(af[m], bv[n], acc[m][n], 0, 0, 0);
  }

#pragma unroll
  for (int m = 0; m < 4; ++m) {
#pragma unroll
    for (int r = 0; r < 4; ++r) {
      const int row = m0 + wr * 64 + m * 16 + lg * 4 + r;  // C/D: row=(lane>>4)*4+reg
      size_t drow = (size_t)row;
      if (EPI == 1) {  // window-order row -> original token index (incl. roll back +4)
        int w = row >> 6, tt = row & 63;
        int bb = w / 49, wi = w - bb * 49;
        int wh = wi / 7, ww = wi - wh * 7;
        int fi = (wh * 8 + (tt >> 3) + 4) % 56;
        int fj = (ww * 8 + (tt & 7) + 4) % 56;
        drow = (size_t)bb * 3136 + fi * 56 + fj;
      }
#pragma unroll
      for (int n = 0; n < 4; ++n) {
        const int col = n0 + wc * 64 + n * 16 + lr;        // C/D: col=lane&15
        float v = acc[m][n][r] + bias[col];
        if (EPI == 0) {
          obf[(size_t)row * N + col] = f2bf(v);
        } else if (EPI == 1) {
          size_t o = drow * 384 + col;
          of[o] = res[o] + v;
        } else if (EPI == 2) {
          v = 0.5f * v * (1.f + erff(v * 0.70710678118f));
          obf[(size_t)row * N + col] = f2bf(v);
        } else {
          size_t o = (size_t)row * 384 + col;
          of[o] = res[o] + v;   // res aliases of (y); same element read-then-write
        }
      }
    }
  }
}

// ---- attention: one wave per (window, head) ----
__global__ __launch_bounds__(64) void attn_k(const s16* __restrict__ qkv,
    const float* __restrict__ rel_bias, const int* __restrict__ rel_index,
    const float* __restrict__ mask, float* __restrict__ probs, s16* __restrict__ aout) {
  __shared__ s16 VT[32][72];  // V^T [d][j], pad to 72 (144B row stride)
  __shared__ s16 P[64][72];   // softmax probs bf16 [i][j]
  const int blk = blockIdx.x;
  const int w = blk / 12, nh = blk - w * 12;
  const int lane = threadIdx.x;
  const int lr = lane & 15, lg = lane >> 4;
  const s16* base = qkv + (size_t)w * 64 * 1152;

  {  // stage V^T: lane handles V row j=lane (32 d's)
    const s16* vrow = base + (size_t)lane * 1152 + 768 + nh * 32;
    s16x8 v0 = *reinterpret_cast<const s16x8*>(vrow);
    s16x8 v1 = *reinterpret_cast<const s16x8*>(vrow + 8);
    s16x8 v2 = *reinterpret_cast<const s16x8*>(vrow + 16);
    s16x8 v3 = *reinterpret_cast<const s16x8*>(vrow + 24);
#pragma unroll
    for (int d = 0; d < 8; ++d) {
      VT[d][lane] = v0[d];
      VT[8 + d][lane] = v1[d];
      VT[16 + d][lane] = v2[d];
      VT[24 + d][lane] = v3[d];
    }
  }

  bf16x8 qf[4], kf[4];
#pragma unroll
  for (int m = 0; m < 4; ++m)
    qf[m] = *reinterpret_cast<const bf16x8*>(base + (size_t)(m * 16 + lr) * 1152 + nh * 32 + lg * 8);
#pragma unroll
  for (int n = 0; n < 4; ++n)
    kf[n] = *reinterpret_cast<const bf16x8*>(base + (size_t)(n * 16 + lr) * 1152 + 384 + nh * 32 + lg * 8);

  f32x4 s[4][4] = {};
#pragma unroll
  for (int m = 0; m < 4; ++m)
#pragma unroll
    for (int n = 0; n < 4; ++n)
      s[m][n] = __builtin_amdgcn_mfma_f32_16x16x32_bf16(qf[m], kf[n], s[m][n], 0, 0, 0);

  const float scale = 0.1767766952966369f;  // 1/sqrt(32)
  const float* mrow = mask + (size_t)(w % 49) * 4096;
#pragma unroll
  for (int m = 0; m < 4; ++m)
#pragma unroll
    for (int n = 0; n < 4; ++n)
#pragma unroll
      for (int r = 0; r < 4; ++r) {
        int i = m * 16 + lg * 4 + r, j = n * 16 + lr;
        s[m][n][r] = s[m][n][r] * scale
                   + rel_bias[(size_t)rel_index[i * 64 + j] * 12 + nh]
                   + mrow[i * 64 + j];
      }
  // row softmax: row i lives on the 16 lanes sharing lg, spread over n
#pragma unroll
  for (int m = 0; m < 4; ++m)
#pragma unroll
    for (int r = 0; r < 4; ++r) {
      float mx = fmaxf(fmaxf(s[m][0][r], s[m][1][r]), fmaxf(s[m][2][r], s[m][3][r]));
#pragma unroll
      for (int o = 1; o < 16; o <<= 1) mx = fmaxf(mx, __shfl_xor(mx, o, 64));
      float sum = 0.f;
#pragma unroll
      for (int n = 0; n < 4; ++n) {
        float e = __expf(s[m][n][r] - mx);
        s[m][n][r] = e;
        sum += e;
      }
#pragma unroll
      for (int o = 1; o < 16; o <<= 1) sum += __shfl_xor(sum, o, 64);
      float inv = 1.f / sum;
#pragma unroll
      for (int n = 0; n < 4; ++n) s[m][n][r] *= inv;
    }
  // write probs (f32, output 1) + stage P (bf16) for PV
  float* prow = probs + (size_t)(w * 12 + nh) * 4096;
#pragma unroll
  for (int m = 0; m < 4; ++m)
#pragma unroll
    for (int n = 0; n < 4; ++n)
#pragma unroll
      for (int r = 0; r < 4; ++r) {
        int i = m * 16 + lg * 4 + r, j = n * 16 + lr;
        float pv = s[m][n][r];
        prow[i * 64 + j] = pv;
        P[i][j] = f2bf(pv);
      }
  __syncthreads();
  // PV: out[i][d] = sum_j P[i][j] V[j][d]
  f32x4 o2[4][2] = {};
#pragma unroll
  for (int m = 0; m < 4; ++m)
#pragma unroll
    for (int kk = 0; kk < 2; ++kk) {
      bf16x8 pa = *reinterpret_cast<const bf16x8*>(&P[m * 16 + lr][kk * 32 + lg * 8]);
#pragma unroll
      for (int n = 0; n < 2; ++n) {
        bf16x8 vb = *reinterpret_cast<const bf16x8*>(&VT[n * 16 + lr][kk * 32 + lg * 8]);
        o2[m][n] = __builtin_amdgcn_mfma_f32_16x16x32_bf16(pa, vb, o2[m][n], 0, 0, 0);
      }
    }
#pragma unroll
  for (int m = 0; m < 4; ++m)
#pragma unroll
    for (int n = 0; n < 2; ++n)
#pragma unroll
      for (int r = 0; r < 4; ++r) {
        int i = m * 16 + lg * 4 + r, d = n * 16 + lr;
        aout[((size_t)w * 64 + i) * 384 + nh * 32 + d] = f2bf(o2[m][n][r]);
      }
}

extern "C" void kernel_launch(void* const* d_in, const int* in_sizes, int n_in,
                              void* d_out, int out_size, void* d_ws, size_t ws_size,
                              hipStream_t stream) {
  const float* x        = (const float*)d_in[0];
  const float* n1g      = (const float*)d_in[1];
  const float* n1b      = (const float*)d_in[2];
  const float* qkv_w    = (const float*)d_in[3];
  const float* qkv_b    = (const float*)d_in[4];
  const float* proj_w   = (const float*)d_in[5];
  const float* proj_b   = (const float*)d_in[6];
  const float* rel_bias = (const float*)d_in[7];
  const float* n2g      = (const float*)d_in[8];
  const float* n2b      = (const float*)d_in[9];
  const float* fc1_w    = (const float*)d_in[10];
  const float* fc1_b    = (const float*)d_in[11];
  const float* fc2_w    = (const float*)d_in[12];
  const float* fc2_b    = (const float*)d_in[13];
  const int*   rel_idx  = (const int*)d_in[14];
  const float* amask    = (const float*)d_in[15];

  float* out   = (float*)d_out;
  float* probs = out + (size_t)ROWS * 384;  // output tuple: y then attn

  // workspace layout (bf16 elements); E(hid) reuses B+C span after they die
  s16* wqkvT = (s16*)d_ws;                         // [1152,384]
  s16* wprojT = wqkvT + 1152 * 384;                // [384,384]
  s16* wfc1T = wprojT + 384 * 384;                 // [1536,384]
  s16* wfc2T = wfc1T + 1536 * 384;                 // [384,1536]
  s16* bufA = wfc2T + 384 * 1536;                  // xln / h2 : ROWS*384
  s16* bufB = bufA + (size_t)ROWS * 384;           // qkv: ROWS*1152 ; later hid: ROWS*1536
  s16* bufC = bufB + (size_t)ROWS * 1152;          // attnout: ROWS*384

  // weights -> bf16 transposed
  convT<<<(1152 * 384) / 256, 256, 0, stream>>>(qkv_w, wqkvT, 384, 1152);
  convT<<<(384 * 384) / 256, 256, 0, stream>>>(proj_w, wprojT, 384, 384);
  convT<<<(1536 * 384) / 256, 256, 0, stream>>>(fc1_w, wfc1T, 384, 1536);
  convT<<<(384 * 1536) / 256, 256, 0, stream>>>(fc2_w, wfc2T, 1536, 384);

  // LN1 (+ shift/window permute) -> xln (window-order rows)
  ln_k<<<ROWS / 4, 256, 0, stream>>>(x, n1g, n1b, bufA, 1);
  // qkv GEMM
  gemm_bt<0><<<dim3(1152 / 128, ROWS / 128), 256, 0, stream>>>(bufA, wqkvT, qkv_b, 384, 1152, bufB, nullptr, nullptr);
  // attention per (window, head)
  attn_k<<<784 * 12, 64, 0, stream>>>(bufB, rel_bias, rel_idx, amask, probs, bufC);
  // proj GEMM + window reverse + unroll + residual -> y (d_out)
  gemm_bt<1><<<dim3(384 / 128, ROWS / 128), 256, 0, stream>>>(bufC, wprojT, proj_b, 384, 384, nullptr, out, x);
  // LN2 -> h2
  ln_k<<<ROWS / 4, 256, 0, stream>>>(out, n2g, n2b, bufA, 0);
  // fc1 + GELU -> hid (bf16)
  gemm_bt<2><<<dim3(1536 / 128, ROWS / 128), 256, 0, stream>>>(bufA, wfc1T, fc1_b, 384, 1536, bufB, nullptr, nullptr);
  // fc2 + residual -> y final (d_out)
  gemm_bt<3><<<dim3(384 / 128, ROWS / 128), 256, 0, stream>>>(bufB, wfc2T, fc2_b, 1536, 384, nullptr, out, out);
}

// Round 2
// 547.840 us; speedup vs baseline: 1.3155x; 1.3155x over previous
//
#include <hip/hip_runtime.h>
#include <hip/hip_bf16.h>
#include <math.h>

// Problem constants
// B=16, H=W=56, C=384, WS=8, SHIFT=4, NH=12, hd=32, N=64, nW=49, B_=784
#define ROWS 50176

typedef short s16;
typedef unsigned int u32;
typedef __attribute__((ext_vector_type(4))) float f32x4;
typedef __attribute__((ext_vector_type(8))) short s16x8;
typedef __attribute__((ext_vector_type(8))) __bf16 bf16x8;

typedef __attribute__((address_space(1))) const u32 gu32;
typedef __attribute__((address_space(3))) u32 lu32;

__device__ __forceinline__ void gload16(const void* g, void* l) {
  __builtin_amdgcn_global_load_lds((gu32*)g, (lu32*)l, 16, 0, 0);
}

__device__ __forceinline__ s16 f2bf(float f) {
  unsigned u = __float_as_uint(f);
  u = (u + 0x7fffu + ((u >> 16) & 1u)) >> 16;  // RNE
  return (s16)u;
}

// ---- weight convert + transpose: src[K][N] f32 -> dst[N][K] bf16 ----
__global__ void convT(const float* __restrict__ src, s16* __restrict__ dst, int K, int N) {
  int i = blockIdx.x * 256 + threadIdx.x;
  if (i >= K * N) return;
  int n = i / K, k = i - n * K;
  dst[i] = f2bf(src[(size_t)k * N + n]);
}

// ---- LayerNorm f32 -> bf16; window_map=1 applies roll(-4,-4)+window partition ----
__global__ __launch_bounds__(256) void ln_k(const float* __restrict__ x,
    const float* __restrict__ g, const float* __restrict__ b,
    s16* __restrict__ out, int window_map) {
  int r = blockIdx.x * 4 + (threadIdx.x >> 6);
  int lane = threadIdx.x & 63;
  size_t src;
  if (window_map) {
    int w = r >> 6, t = r & 63;
    int bb = w / 49, wi = w - bb * 49;
    int wh = wi / 7, ww = wi - wh * 7;
    int i = (wh * 8 + (t >> 3) + 4) % 56;
    int j = (ww * 8 + (t & 7) + 4) % 56;
    src = (size_t)bb * 3136 + i * 56 + j;
  } else {
    src = (size_t)r;
  }
  const float* xr = x + src * 384;
  float v[6];
  float s = 0.f;
#pragma unroll
  for (int e = 0; e < 6; ++e) { v[e] = xr[lane + e * 64]; s += v[e]; }
#pragma unroll
  for (int o = 1; o < 64; o <<= 1) s += __shfl_xor(s, o, 64);
  float mu = s * (1.f / 384.f);
  float q = 0.f;
#pragma unroll
  for (int e = 0; e < 6; ++e) { float d = v[e] - mu; q += d * d; }
#pragma unroll
  for (int o = 1; o < 64; o <<= 1) q += __shfl_xor(q, o, 64);
  float rs = rsqrtf(q * (1.f / 384.f) + 1e-5f);
  s16* orow = out + (size_t)r * 384;
#pragma unroll
  for (int e = 0; e < 6; ++e) {
    int c = lane + e * 64;
    orow[c] = f2bf((v[e] - mu) * rs * g[c] + b[c]);
  }
}

// ---- GEMM  C[M,N] = A[M,K]bf16 * BT[N,K]bf16 + bias (m97 structure) ----
// 128x128 tile, BK=64, global_load_lds w16 into linear LDS, XOR chunk swizzle.
// EPI 0: bf16 out (qkv) | 1: window-reverse+unroll+residual -> f32 (proj)
// EPI 2: exact GELU -> bf16 (fc1) | 3: residual -> f32 (fc2)
template<int EPI>
__global__ __launch_bounds__(256) void gemm_bt(const s16* __restrict__ A,
    const s16* __restrict__ BT, const float* __restrict__ bias, int K, int N,
    s16* __restrict__ obf, float* of, const float* res) {
  __shared__ s16 Asm[128 * 64];  // linear [row][64], 128B/row
  __shared__ s16 Bsm[128 * 64];
  const int t = threadIdx.x;
  const int nbx = N >> 7;
  // bijective XCD swizzle (m204)
  const int nwg = gridDim.x;
  {
  }
  int id = blockIdx.x;
  const int q8 = nwg >> 3, r8 = nwg & 7;
  const int xcd = id & 7, loc = id >> 3;
  const int swz = (xcd < r8 ? xcd * (q8 + 1) : r8 * (q8 + 1) + (xcd - r8) * q8) + loc;
  const int by = swz / nbx, bx = swz - by * nbx;
  const int m0 = by * 128, n0 = bx * 128;

  const int wv = t >> 6, lane = t & 63;
  const int wr = wv >> 1, wc = wv & 1;
  const int lr = lane & 15, lg = lane >> 4;

  // staging addresses: linear LDS offset o -> (row, physical chunk pc);
  // source uses logical chunk lc = pc ^ (row&7)  (XOR involution; read applies same XOR)
  const s16* asrc[4]; const s16* bsrc[4];
  char* adst[4]; char* bdst[4];
#pragma unroll
  for (int i = 0; i < 4; ++i) {
    int o = (i * 256 + t) * 16;
    int row = o >> 7, pc = (o >> 4) & 7, lc = pc ^ (row & 7);
    asrc[i] = A + (size_t)(m0 + row) * K + lc * 8;
    adst[i] = (char*)Asm + o;
    bsrc[i] = BT + (size_t)(n0 + row) * K + lc * 8;
    bdst[i] = (char*)Bsm + o;
  }

  f32x4 acc[4][4] = {};

  for (int k0 = 0; k0 < K; k0 += 64) {
#pragma unroll
    for (int i = 0; i < 4; ++i) {
      gload16(asrc[i] + k0, adst[i]);
      gload16(bsrc[i] + k0, bdst[i]);
    }
    __syncthreads();  // vmcnt(0) drain + barrier
    bf16x8 af[2][4], bv[2][4];
#pragma unroll
    for (int kk = 0; kk < 2; ++kk) {
      const int cb = ((kk << 2) | lg) ^ (lr & 7);  // swizzled read chunk
#pragma unroll
      for (int m = 0; m < 4; ++m) {
        af[kk][m] = *reinterpret_cast<const bf16x8*>(
            (const char*)Asm + (wr * 64 + m * 16 + lr) * 128 + cb * 16);
        bv[kk][m] = *reinterpret_cast<const bf16x8*>(
            (const char*)Bsm + (wc * 64 + m * 16 + lr) * 128 + cb * 16);
      }
    }
#pragma unroll
    for (int kk = 0; kk < 2; ++kk)
#pragma unroll
      for (int m = 0; m < 4; ++m)
#pragma unroll
        for (int n = 0; n < 4; ++n)
          acc[m][n] = __builtin_amdgcn_mfma_f32_16x16x32_bf16(af[kk][m], bv[kk][n], acc[m][n], 0, 0, 0);
    __syncthreads();  // reads done before next stage
  }

#pragma unroll
  for (int m = 0; m < 4; ++m) {
#pragma unroll
    for (int r = 0; r < 4; ++r) {
      const int row = m0 + wr * 64 + m * 16 + lg * 4 + r;  // C/D: row=(lane>>4)*4+reg
      size_t drow = (size_t)row;
      if (EPI == 1) {
        int w = row >> 6, tt = row & 63;
        int bb = w / 49, wi = w - bb * 49;
        int wh = wi / 7, ww = wi - wh * 7;
        int fi = (wh * 8 + (tt >> 3) + 4) % 56;
        int fj = (ww * 8 + (tt & 7) + 4) % 56;
        drow = (size_t)bb * 3136 + fi * 56 + fj;
      }
#pragma unroll
      for (int n = 0; n < 4; ++n) {
        const int col = n0 + wc * 64 + n * 16 + lr;        // C/D: col=lane&15
        float v = acc[m][n][r] + bias[col];
        if (EPI == 0) {
          obf[(size_t)row * N + col] = f2bf(v);
        } else if (EPI == 1) {
          size_t o = drow * 384 + col;
          of[o] = res[o] + v;
        } else if (EPI == 2) {
          v = 0.5f * v * (1.f + erff(v * 0.70710678118f));
          obf[(size_t)row * N + col] = f2bf(v);
        } else {
          size_t o = (size_t)row * 384 + col;
          of[o] = res[o] + v;
        }
      }
    }
  }
}

// ---- attention: one wave per (window, head) ----
__global__ __launch_bounds__(64) void attn_k(const s16* __restrict__ qkv,
    const float* __restrict__ rel_bias, const int* __restrict__ rel_index,
    const float* __restrict__ mask, float* __restrict__ probs, s16* __restrict__ aout) {
  __shared__ s16 VT[32][72];
  __shared__ s16 P[64][72];
  const int blk = blockIdx.x;
  const int w = blk / 12, nh = blk - w * 12;
  const int lane = threadIdx.x;
  const int lr = lane & 15, lg = lane >> 4;
  const s16* base = qkv + (size_t)w * 64 * 1152;

  {
    const s16* vrow = base + (size_t)lane * 1152 + 768 + nh * 32;
    s16x8 v0 = *reinterpret_cast<const s16x8*>(vrow);
    s16x8 v1 = *reinterpret_cast<const s16x8*>(vrow + 8);
    s16x8 v2 = *reinterpret_cast<const s16x8*>(vrow + 16);
    s16x8 v3 = *reinterpret_cast<const s16x8*>(vrow + 24);
#pragma unroll
    for (int d = 0; d < 8; ++d) {
      VT[d][lane] = v0[d];
      VT[8 + d][lane] = v1[d];
      VT[16 + d][lane] = v2[d];
      VT[24 + d][lane] = v3[d];
    }
  }

  bf16x8 qf[4], kf[4];
#pragma unroll
  for (int m = 0; m < 4; ++m)
    qf[m] = *reinterpret_cast<const bf16x8*>(base + (size_t)(m * 16 + lr) * 1152 + nh * 32 + lg * 8);
#pragma unroll
  for (int n = 0; n < 4; ++n)
    kf[n] = *reinterpret_cast<const bf16x8*>(base + (size_t)(n * 16 + lr) * 1152 + 384 + nh * 32 + lg * 8);

  f32x4 s[4][4] = {};
#pragma unroll
  for (int m = 0; m < 4; ++m)
#pragma unroll
    for (int n = 0; n < 4; ++n)
      s[m][n] = __builtin_amdgcn_mfma_f32_16x16x32_bf16(qf[m], kf[n], s[m][n], 0, 0, 0);

  const float scale = 0.1767766952966369f;
  const float* mrow = mask + (size_t)(w % 49) * 4096;
#pragma unroll
  for (int m = 0; m < 4; ++m)
#pragma unroll
    for (int n = 0; n < 4; ++n)
#pragma unroll
      for (int r = 0; r < 4; ++r) {
        int i = m * 16 + lg * 4 + r, j = n * 16 + lr;
        s[m][n][r] = s[m][n][r] * scale
                   + rel_bias[(size_t)rel_index[i * 64 + j] * 12 + nh]
                   + mrow[i * 64 + j];
      }
#pragma unroll
  for (int m = 0; m < 4; ++m)
#pragma unroll
    for (int r = 0; r < 4; ++r) {
      float mx = fmaxf(fmaxf(s[m][0][r], s[m][1][r]), fmaxf(s[m][2][r], s[m][3][r]));
#pragma unroll
      for (int o = 1; o < 16; o <<= 1) mx = fmaxf(mx, __shfl_xor(mx, o, 64));
      float sum = 0.f;
#pragma unroll
      for (int n = 0; n < 4; ++n) {
        float e = __expf(s[m][n][r] - mx);
        s[m][n][r] = e;
        sum += e;
      }
#pragma unroll
      for (int o = 1; o < 16; o <<= 1) sum += __shfl_xor(sum, o, 64);
      float inv = 1.f / sum;
#pragma unroll
      for (int n = 0; n < 4; ++n) s[m][n][r] *= inv;
    }
  float* prow = probs + (size_t)(w * 12 + nh) * 4096;
#pragma unroll
  for (int m = 0; m < 4; ++m)
#pragma unroll
    for (int n = 0; n < 4; ++n)
#pragma unroll
      for (int r = 0; r < 4; ++r) {
        int i = m * 16 + lg * 4 + r, j = n * 16 + lr;
        float pv = s[m][n][r];
        prow[i * 64 + j] = pv;
        P[i][j] = f2bf(pv);
      }
  __syncthreads();
  f32x4 o2[4][2] = {};
#pragma unroll
  for (int m = 0; m < 4; ++m)
#pragma unroll
    for (int kk = 0; kk < 2; ++kk) {
      bf16x8 pa = *reinterpret_cast<const bf16x8*>(&P[m * 16 + lr][kk * 32 + lg * 8]);
#pragma unroll
      for (int n = 0; n < 2; ++n) {
        bf16x8 vb = *reinterpret_cast<const bf16x8*>(&VT[n * 16 + lr][kk * 32 + lg * 8]);
        o2[m][n] = __builtin_amdgcn_mfma_f32_16x16x32_bf16(pa, vb, o2[m][n], 0, 0, 0);
      }
    }
#pragma unroll
  for (int m = 0; m < 4; ++m)
#pragma unroll
    for (int n = 0; n < 2; ++n)
#pragma unroll
      for (int r = 0; r < 4; ++r) {
        int i = m * 16 + lg * 4 + r, d = n * 16 + lr;
        aout[((size_t)w * 64 + i) * 384 + nh * 32 + d] = f2bf(o2[m][n][r]);
      }
}

extern "C" void kernel_launch(void* const* d_in, const int* in_sizes, int n_in,
                              void* d_out, int out_size, void* d_ws, size_t ws_size,
                              hipStream_t stream) {
  const float* x        = (const float*)d_in[0];
  const float* n1g      = (const float*)d_in[1];
  const float* n1b      = (const float*)d_in[2];
  const float* qkv_w    = (const float*)d_in[3];
  const float* qkv_b    = (const float*)d_in[4];
  const float* proj_w   = (const float*)d_in[5];
  const float* proj_b   = (const float*)d_in[6];
  const float* rel_bias = (const float*)d_in[7];
  const float* n2g      = (const float*)d_in[8];
  const float* n2b      = (const float*)d_in[9];
  const float* fc1_w    = (const float*)d_in[10];
  const float* fc1_b    = (const float*)d_in[11];
  const float* fc2_w    = (const float*)d_in[12];
  const float* fc2_b    = (const float*)d_in[13];
  const int*   rel_idx  = (const int*)d_in[14];
  const float* amask    = (const float*)d_in[15];

  float* out   = (float*)d_out;
  float* probs = out + (size_t)ROWS * 384;

  s16* wqkvT = (s16*)d_ws;
  s16* wprojT = wqkvT + 1152 * 384;
  s16* wfc1T = wprojT + 384 * 384;
  s16* wfc2T = wfc1T + 1536 * 384;
  s16* bufA = wfc2T + 384 * 1536;
  s16* bufB = bufA + (size_t)ROWS * 384;
  s16* bufC = bufB + (size_t)ROWS * 1152;

  convT<<<(1152 * 384) / 256, 256, 0, stream>>>(qkv_w, wqkvT, 384, 1152);
  convT<<<(384 * 384) / 256, 256, 0, stream>>>(proj_w, wprojT, 384, 384);
  convT<<<(1536 * 384) / 256, 256, 0, stream>>>(fc1_w, wfc1T, 384, 1536);
  convT<<<(384 * 1536) / 256, 256, 0, stream>>>(fc2_w, wfc2T, 1536, 384);

  ln_k<<<ROWS / 4, 256, 0, stream>>>(x, n1g, n1b, bufA, 1);
  gemm_bt<0><<<(1152 / 128) * (ROWS / 128), 256, 0, stream>>>(bufA, wqkvT, qkv_b, 384, 1152, bufB, nullptr, nullptr);
  attn_k<<<784 * 12, 64, 0, stream>>>(bufB, rel_bias, rel_idx, amask, probs, bufC);
  gemm_bt<1><<<(384 / 128) * (ROWS / 128), 256, 0, stream>>>(bufC, wprojT, proj_b, 384, 384, nullptr, out, x);
  ln_k<<<ROWS / 4, 256, 0, stream>>>(out, n2g, n2b, bufA, 0);
  gemm_bt<2><<<(1536 / 128) * (ROWS / 128), 256, 0, stream>>>(bufA, wfc1T, fc1_b, 384, 1536, bufB, nullptr, nullptr);
  gemm_bt<3><<<(384 / 128) * (ROWS / 128), 256, 0, stream>>>(bufB, wfc2T, fc2_b, 1536, 384, nullptr, out, out);
}